// Round 14
// baseline (382.452 us; speedup 1.0000x reference)
//
#include <hip/hip_runtime.h>

// MHA-no-softmax, re-associated:  out = rope(XWq+bq) · [ (rope(XWk+bk))^T (XWv+bv) ] / 4
// Round 11: T4 counted-vmcnt on the 256x256 dbuf kernel. Round-10 showed the
// per-K-step __syncthreads (compiler drains vmcnt(0)) serializes each K-step's
// 8.4MB HBM burst (~3200cyc) behind compute -> MfmaUtil 20%. Fix: raw s_barrier
// + "s_waitcnt vmcnt(8)" so next tile's 8 loads/wave stay in flight across BOTH
// barriers (m218 pattern). RAW: vmcnt(8)+bar before COMPUTE(buf); WAR: bar after
// COMPUTE before re-staging that buffer. sched_barrier(0) fences (rule #18).
// ktv/reduce/casts untouched (within-probe control).

typedef _Float16 f16;
typedef _Float16 f16x8 __attribute__((ext_vector_type(8)));
typedef _Float16 f16x4 __attribute__((ext_vector_type(4)));
typedef float f32x4 __attribute__((ext_vector_type(4)));

namespace {
constexpr int kB = 4, kS = 4096, kD = 1024;
constexpr int kBS = kB * kS;  // 16384
constexpr int TM = 128, TN = 128, BK = 64;  // (TM/TN used by legacy ktv kernel)
enum { EPI_QPROJ, EPI_KPROJ, EPI_VPROJ, EPI_KTV, EPI_QM };
}  // namespace

__device__ __forceinline__ void gld_lds16(const f16* g, f16* l) {
  __builtin_amdgcn_global_load_lds(
      (const __attribute__((address_space(1))) unsigned int*)g,
      (__attribute__((address_space(3))) unsigned int*)l, 16, 0, 0);
}

__global__ void cast_f2h(const float* __restrict__ src, f16* __restrict__ dst,
                         int n) {
  const int stride = gridDim.x * blockDim.x * 8;
  for (int i = (blockIdx.x * blockDim.x + threadIdx.x) * 8; i < n; i += stride) {
    float4 a = *reinterpret_cast<const float4*>(src + i);
    float4 b = *reinterpret_cast<const float4*>(src + i + 4);
    f16x8 o = {(f16)a.x, (f16)a.y, (f16)a.z, (f16)a.w,
               (f16)b.x, (f16)b.y, (f16)b.z, (f16)b.w};
    *reinterpret_cast<f16x8*>(dst + i) = o;
  }
}

// partials p[(b*2+split)][1M] fp32 -> Mt[b][1M] f16
__global__ void reduce_mt(const float* __restrict__ p, f16* __restrict__ mt) {
  const int i = (blockIdx.x * blockDim.x + threadIdx.x) * 8;  // < 4M
  const int b = i >> 20;
  const int w = i & ((1 << 20) - 1);
  const float* p0 = p + ((size_t)(2 * b) << 20) + w;
  const float* p1 = p0 + (1 << 20);
  float4 a0 = *reinterpret_cast<const float4*>(p0);
  float4 a1 = *reinterpret_cast<const float4*>(p0 + 4);
  float4 c0 = *reinterpret_cast<const float4*>(p1);
  float4 c1 = *reinterpret_cast<const float4*>(p1 + 4);
  f16x8 o = {(f16)(a0.x + c0.x), (f16)(a0.y + c0.y), (f16)(a0.z + c0.z),
             (f16)(a0.w + c0.w), (f16)(a1.x + c1.x), (f16)(a1.y + c1.y),
             (f16)(a1.z + c1.z), (f16)(a1.w + c1.w)};
  *reinterpret_cast<f16x8*>(mt + i) = o;
}

// ============ 256x256 / BK=64 / 512-thr / 8-wave / dbuf + counted vmcnt =======
template <int EPI, int LDA, int LDB, int KSTEPS>
__global__ __launch_bounds__(512, 2) void gemm256(
    const f16* __restrict__ A, const f16* __restrict__ B,
    const float* __restrict__ bias, const float* __restrict__ fcos,
    const float* __restrict__ fsin, void* __restrict__ Cout) {
  // sA[2][256][64] + sB[2][256][64] f16 = 128 KiB (dbuf); epilogue tbuf aliases
  __shared__ __align__(16) unsigned char smem_raw[131072];
  f16* sAq = (f16*)smem_raw;   // 2 x 16384 f16
  f16* sBq = sAq + 32768;      // 2 x 16384 f16

  const int tid = threadIdx.x;
  const int w = tid >> 6, lane = tid & 63;
  const int wm = w >> 2, wn = w & 3;  // 2M x 4N wave grid; wave tile 128x64

  // XCD c (=bid%8) owns mtiles [8c,8c+8), ntiles inner
  const int bid = blockIdx.x;
  const int l = (bid & 7) * 32 + (bid >> 3);  // grid 256 -> bijective
  const int mt = (l >> 5) * 8 + ((l & 31) >> 2);
  const int nt = l & 3;
  const int m0 = mt * 256, n0 = nt * 256;

  const f16* Ab = A + (size_t)m0 * LDA;
  const f16* Bb = B + (size_t)n0 * LDB +
                  (EPI == EPI_QM ? (size_t)(m0 >> 12) * kD * kD : (size_t)0);

  const int srow = lane >> 3;         // staging: row within 8-row chunk
  const int scolb = (lane & 7) * 16;  // col bytes within 128B row

  f32x4 acc[8][4];
#pragma unroll
  for (int i = 0; i < 8; ++i)
#pragma unroll
    for (int j = 0; j < 4; ++j) acc[i][j] = (f32x4){0.f, 0.f, 0.f, 0.f};

  // stage one K-tile (A:256x64 + B:256x64) into buffer `buf` (8 loads/wave)
  auto STAGE = [&](int buf, int ks) {
    const int k0 = ks * BK;
#pragma unroll
    for (int i = 0; i < 4; ++i) {
      const int row = w * 32 + i * 8 + srow;
      const int fe = (scolb ^ ((row & 7) << 4)) >> 1;  // inverse-swizzled src
      gld_lds16(Ab + (size_t)row * LDA + k0 + fe,
                sAq + buf * 16384 + w * 2048 + i * 512);
      gld_lds16(Bb + (size_t)row * LDB + k0 + fe,
                sBq + buf * 16384 + w * 2048 + i * 512);
    }
  };

  auto COMPUTE = [&](int buf) {
    const f16* bA = sAq + buf * 16384;
    const f16* bB = sBq + buf * 16384;
#pragma unroll
    for (int kc = 0; kc < 2; ++kc) {
      const int clog = kc * 64 + (lane >> 4) * 16;  // logical col bytes
      f16x8 af[8], bf[4];
#pragma unroll
      for (int f = 0; f < 8; ++f) {
        const int ra = wm * 128 + f * 16 + (lane & 15);
        af[f] = *reinterpret_cast<const f16x8*>(
            bA + ra * 64 + ((clog ^ ((ra & 7) << 4)) >> 1));
      }
#pragma unroll
      for (int f = 0; f < 4; ++f) {
        const int rb = wn * 64 + f * 16 + (lane & 15);
        bf[f] = *reinterpret_cast<const f16x8*>(
            bB + rb * 64 + ((clog ^ ((rb & 7) << 4)) >> 1));
      }
#pragma unroll
      for (int i = 0; i < 8; ++i)
#pragma unroll
        for (int j = 0; j < 4; ++j)
          acc[i][j] = __builtin_amdgcn_mfma_f32_16x16x32_f16(af[i], bf[j],
                                                             acc[i][j], 0, 0, 0);
    }
  };

  // Counted-vmcnt dbuf pipeline (T4): loads for tile t+1 stay in flight across
  // both barriers; never drain vmcnt to 0 until the final tile.
  STAGE(0, 0);
  int buf = 0;
  for (int t = 0; t < KSTEPS; ++t) {
    if (t + 1 < KSTEPS) {
      STAGE(buf ^ 1, t + 1);  // buf^1 freed by end-of-iter-(t-1) barrier
      asm volatile("s_waitcnt vmcnt(8)" ::: "memory");  // tile t's 8 retired
    } else {
      asm volatile("s_waitcnt vmcnt(0)" ::: "memory");
    }
    __builtin_amdgcn_sched_barrier(0);
    __builtin_amdgcn_s_barrier();  // raw: no vmcnt drain
    __builtin_amdgcn_sched_barrier(0);
    COMPUTE(buf);
    if (t + 1 < KSTEPS) {
      __builtin_amdgcn_s_barrier();  // WAR: all waves done reading buf
      __builtin_amdgcn_sched_barrier(0);
    }
    buf ^= 1;
  }

  // C/D: row = rb0 + fm*16 + j, col = n0 + cloc + fn*16
  const int rb0 = m0 + wm * 128 + (lane >> 4) * 4;
  const int cloc = wn * 64 + (lane & 15);

  if constexpr (EPI == EPI_QM) {
    float* C = (float*)Cout;
#pragma unroll
    for (int fm = 0; fm < 8; ++fm)
#pragma unroll
      for (int fn = 0; fn < 4; ++fn)
#pragma unroll
        for (int j = 0; j < 4; ++j)
          C[(size_t)(rb0 + fm * 16 + j) * kD + n0 + cloc + fn * 16] =
              0.25f * acc[fm][fn][j];
  } else {
    // bias (+rope for Q/K) in fp32
#pragma unroll
    for (int fn = 0; fn < 4; ++fn) {
      const int colF = n0 + cloc + fn * 16;
      const float bvv = bias[colF];
#pragma unroll
      for (int fm = 0; fm < 8; ++fm)
#pragma unroll
        for (int j = 0; j < 4; ++j) {
          float v = acc[fm][fn][j] + bvv;
          if constexpr (EPI == EPI_QPROJ || EPI == EPI_KPROJ) {
            const int s = (rb0 + fm * 16 + j) & (kS - 1);
            const float cc = fcos[s * (kD / 2) + (colF >> 1)];
            const float ss = fsin[s * (kD / 2) + (colF >> 1)];
            const float p = __shfl_xor(v, 1);  // partner col (colF^1)
            v = (colF & 1) ? (p * ss + v * cc) : (v * cc - p * ss);
          }
          acc[fm][fn][j] = v;
        }
    }
    if constexpr (EPI == EPI_QPROJ) {
      f16* C = (f16*)Cout;
#pragma unroll
      for (int fm = 0; fm < 8; ++fm)
#pragma unroll
        for (int fn = 0; fn < 4; ++fn)
#pragma unroll
          for (int j = 0; j < 4; ++j)
            C[(size_t)(rb0 + fm * 16 + j) * kD + n0 + cloc + fn * 16] =
                (f16)acc[fm][fn][j];
    } else {
      // K/V: transposed store [b][feat][s], two 128-feat passes through LDS
      __syncthreads();  // sA/sB dead -> reuse as tbuf [128][264] f16 (67.5KB)
      f16* tbuf = (f16*)smem_raw;
      const int bidx = m0 >> 12;
      const int sbase = m0 & (kS - 1);
      f16* Ct = (f16*)Cout + (size_t)bidx * kD * kS + sbase;
#pragma unroll
      for (int h = 0; h < 2; ++h) {
        if ((wn >> 1) == h) {
#pragma unroll
          for (int fm = 0; fm < 8; ++fm)
#pragma unroll
            for (int fn = 0; fn < 4; ++fn) {
              f16x4 pk = {(f16)acc[fm][fn][0], (f16)acc[fm][fn][1],
                          (f16)acc[fm][fn][2], (f16)acc[fm][fn][3]};
              const int rT = (wn & 1) * 64 + fn * 16 + (lane & 15);  // feat&127
              const int cT = wm * 128 + fm * 16 + (lane >> 4) * 4;   // s-dim
              *reinterpret_cast<f16x4*>(tbuf + rT * 264 + cT) = pk;
            }
        }
        __syncthreads();
#pragma unroll
        for (int it = 0; it < 8; ++it) {
          const int idx = it * 512 + tid;
          const int rn = idx >> 5, ch = idx & 31;
          f16x8 vv = *reinterpret_cast<const f16x8*>(tbuf + rn * 264 + ch * 8);
          *reinterpret_cast<f16x8*>(
              Ct + (size_t)(n0 + h * 128 + rn) * kS + ch * 8) = vv;
        }
        __syncthreads();
      }
    }
  }
}

// ============ legacy 128x128 kernel: KTV only (control, unchanged) ===========
template <int EPI, int LDA, int LDB, int KSTEPS>
__global__ __launch_bounds__(256) void gemm_kernel(
    const f16* __restrict__ A, const f16* __restrict__ B,
    const float* __restrict__ bias, const float* __restrict__ fcos,
    const float* __restrict__ fsin, void* __restrict__ Cout) {
  __shared__ __align__(16) unsigned char smem_raw[34816];
  f16* sA = (f16*)smem_raw;
  f16* sB = sA + TM * BK;

  const int tid = threadIdx.x;
  const int w = tid >> 6, lane = tid & 63;
  const int wm = w >> 1, wn = w & 1;

  int m0, n0, zidx = 0;
  const int bid = blockIdx.x;
  {
    const int l = (bid & 7) * 64 + (bid >> 3);  // XCD c owns z==c
    zidx = l >> 6;
    const int i = l & 63;
    m0 = (i >> 3) * TM;  // Vt panel (A)
    n0 = (i & 7) * TN;   // Kt tile  (B)
  }

  size_t aoff = (size_t)m0 * LDA;
  size_t boff = (size_t)n0 * LDB;
  {
    const int b = zidx >> 1, sp = zidx & 1;
    const size_t bo = (size_t)b * kD * kS + (size_t)sp * (kS / 2);
    aoff += bo;
    boff += bo;
  }
  const f16* Ab = A + aoff;
  const f16* Bb = B + boff;

  const int srow = lane >> 3;
  const int scolb = (lane & 7) * 16;

  f32x4 acc[4][4];
#pragma unroll
  for (int i = 0; i < 4; ++i)
#pragma unroll
    for (int j = 0; j < 4; ++j) acc[i][j] = (f32x4){0.f, 0.f, 0.f, 0.f};

  for (int ks = 0; ks < KSTEPS; ++ks) {
    const int k0 = ks * BK;
#pragma unroll
    for (int i = 0; i < 4; ++i) {
      const int row = w * 32 + i * 8 + srow;
      const int fe = (scolb ^ ((row & 7) << 4)) >> 1;
      gld_lds16(Ab + (size_t)row * LDA + k0 + fe, sA + w * 2048 + i * 512);
      gld_lds16(Bb + (size_t)row * LDB + k0 + fe, sB + w * 2048 + i * 512);
    }
    __syncthreads();
#pragma unroll
    for (int kc = 0; kc < 2; ++kc) {
      const int clog = kc * 64 + (lane >> 4) * 16;
      f16x8 af[4], bf[4];
#pragma unroll
      for (int f = 0; f < 4; ++f) {
        const int ra = wm * 64 + f * 16 + (lane & 15);
        af[f] = *reinterpret_cast<const f16x8*>(
            sA + ra * BK + ((clog ^ ((ra & 7) << 4)) >> 1));
        const int rb = wn * 64 + f * 16 + (lane & 15);
        bf[f] = *reinterpret_cast<const f16x8*>(
            sB + rb * BK + ((clog ^ ((rb & 7) << 4)) >> 1));
      }
#pragma unroll
      for (int i = 0; i < 4; ++i)
#pragma unroll
        for (int j = 0; j < 4; ++j)
          acc[i][j] = __builtin_amdgcn_mfma_f32_16x16x32_f16(af[i], bf[j],
                                                             acc[i][j], 0, 0, 0);
    }
    __syncthreads();
  }

  const int rbase = m0 + wm * 64 + (lane >> 4) * 4;
  const int cbase = n0 + wn * 64 + (lane & 15);
  float* C = (float*)Cout + ((size_t)zidx << 20);
#pragma unroll
  for (int fm = 0; fm < 4; ++fm)
#pragma unroll
    for (int fn = 0; fn < 4; ++fn)
#pragma unroll
      for (int j = 0; j < 4; ++j)
        C[(size_t)(rbase + fm * 16 + j) * kD + cbase + fn * 16] = acc[fm][fn][j];
}

extern "C" void kernel_launch(void* const* d_in, const int* in_sizes, int n_in,
                              void* d_out, int out_size, void* d_ws,
                              size_t ws_size, hipStream_t stream) {
  const float* x = (const float*)d_in[0];
  const float* fcos = (const float*)d_in[1];
  const float* fsin = (const float*)d_in[2];
  const float* wq = (const float*)d_in[3];
  const float* bq = (const float*)d_in[4];
  const float* wk = (const float*)d_in[5];
  const float* bk = (const float*)d_in[6];
  const float* wv = (const float*)d_in[7];
  const float* bv = (const float*)d_in[8];

  char* ws = (char*)d_ws;
  f16* xh = (f16*)ws;                              // 32 MiB
  f16* wqh = (f16*)(ws + ((size_t)32 << 20));      // 2 MiB
  f16* wkh = (f16*)(ws + ((size_t)34 << 20));      // 2 MiB
  f16* wvh = (f16*)(ws + ((size_t)36 << 20));      // 2 MiB
  f16* Mt = (f16*)(ws + ((size_t)38 << 20));       // 8 MiB
  float* part = (float*)(ws + ((size_t)46 << 20)); // 32 MiB (dead after reduce)
  f16* qh = (f16*)(ws + ((size_t)46 << 20));       // 32 MiB (aliases part)
  f16* Kt = (f16*)d_out;                           // d_out lo 32 MiB (scratch)
  f16* Vt = (f16*)d_out + ((size_t)16 << 20);      // d_out hi 32 MiB (scratch)

  dim3 blk(256), blk512(512);
  cast_f2h<<<2048, blk, 0, stream>>>(x, xh, kBS * kD);
  cast_f2h<<<512, blk, 0, stream>>>(wq, wqh, kD * kD);
  cast_f2h<<<512, blk, 0, stream>>>(wk, wkh, kD * kD);
  cast_f2h<<<512, blk, 0, stream>>>(wv, wvh, kD * kD);

  gemm256<EPI_KPROJ, kD, kD, kD / BK>
      <<<256, blk512, 0, stream>>>(xh, wkh, bk, fcos, fsin, Kt);
  gemm256<EPI_VPROJ, kD, kD, kD / BK>
      <<<256, blk512, 0, stream>>>(xh, wvh, bv, nullptr, nullptr, Vt);
  gemm_kernel<EPI_KTV, kS, kS, (kS / 2) / BK>
      <<<512, blk, 0, stream>>>(Vt, Kt, nullptr, nullptr, nullptr, part);
  reduce_mt<<<2048, blk, 0, stream>>>(part, Mt);
  gemm256<EPI_QPROJ, kD, kD, kD / BK>
      <<<256, blk512, 0, stream>>>(xh, wqh, bq, fcos, fsin, qh);
  gemm256<EPI_QM, kD, kD, kD / BK>
      <<<256, blk512, 0, stream>>>(qh, Mt, nullptr, nullptr, nullptr,
                                   (float*)d_out);
}